// Round 11
// baseline (478.788 us; speedup 1.0000x reference)
//
#include <hip/hip_runtime.h>

#define N_NODES 100000
#define N_EDGES 1600000
#define D 32
#define ED 8
#define NEG_SLOPE 0.01f
#define BSH 9                                    // bucket shift: 512 nodes/bucket
#define BKN 512                                  // nodes per bucket
#define CB ((N_NODES + BKN - 1) / BKN)           // 196 coarse buckets
#define FB_SPLIT 2                               // fineB sub-blocks per bucket
#define A_EPB 1024                               // edges per A-block
#define A_NB ((N_EDGES + A_EPB - 1) / A_EPB)     // 1563
#define SEG 128                                  // edges per halfwave segment
#define NBLK 98                                  // mid-tier scan blocks

typedef unsigned int uint;
typedef unsigned short ushort;
typedef __fp16 half2v __attribute__((ext_vector_type(2)));

__device__ __forceinline__ uint bf16_rne(float f) {
    uint u = __float_as_uint(f);
    return (u + 0x7fffu + ((u >> 16) & 1u)) >> 16;
}
__device__ __forceinline__ uint pack2(float lo, float hi) {
    return bf16_rne(lo) | (bf16_rne(hi) << 16);
}
__device__ __forceinline__ float bf_lo(uint u) { return __uint_as_float(u << 16); }
__device__ __forceinline__ float bf_hi(uint u) { return __uint_as_float(u & 0xffff0000u); }
__device__ __forceinline__ float bf_us(ushort u) { return __uint_as_float(((uint)u) << 16); }

// pack two floats -> f16x2 (RNE)
__device__ __forceinline__ uint ph2(float lo, float hi) {
    __fp16 l = (__fp16)lo, h = (__fp16)hi;
    return (uint)__builtin_bit_cast(ushort, l) | ((uint)__builtin_bit_cast(ushort, h) << 16);
}

#if defined(__has_builtin) && __has_builtin(__builtin_amdgcn_fdot2)
__device__ __forceinline__ float fdot2f(uint u, half2v w, float c) {
    return __builtin_amdgcn_fdot2(__builtin_bit_cast(half2v, u), w, c, false);
}
#else
__device__ __forceinline__ float fdot2f(uint u, half2v w, float c) {
    half2v a = __builtin_bit_cast(half2v, u);
    return c + (float)a.x * (float)w.x + (float)a.y * (float)w.y;
}
#endif

// ---------------- x -> bf16 pack ----------------
__global__ __launch_bounds__(256) void pack_x_kernel(
    const float* __restrict__ x, ushort* __restrict__ xb)
{
    int i = blockIdx.x * 256 + threadIdx.x;     // over N*D/4
    if (i >= N_NODES * D / 4) return;
    float4 f = ((const float4*)x)[i];
    ((uint2*)xb)[i] = make_uint2(pack2(f.x, f.y), pack2(f.z, f.w));
}

// ---- A1: per-block coarse histogram (LDS), write count matrix ----
__global__ __launch_bounds__(256) void countA_kernel(
    const int* __restrict__ dst, int* __restrict__ cntM)
{
    __shared__ int h[CB];
    const int t = threadIdx.x;
    for (int i = t; i < CB; i += 256) h[i] = 0;
    __syncthreads();
    const int e0 = blockIdx.x * A_EPB;
    for (int j = 0; j < A_EPB; j += 256) {
        int e = e0 + j + t;
        if (e < N_EDGES) atomicAdd(&h[dst[e] >> BSH], 1);
    }
    __syncthreads();
    for (int i = t; i < CB; i += 256) cntM[blockIdx.x * CB + i] = h[i];
}

// ---- S1: per-bucket exclusive scan over blocks (A_NB <= 2048) ----
// 1024 threads, 2 elements per thread (pair-local reconstruction).
__global__ __launch_bounds__(1024) void scanS1_kernel(
    const int* __restrict__ cntM, int* __restrict__ exclM, int* __restrict__ btot)
{
    __shared__ int s[1024];
    const int t = threadIdx.x;
    const int b = blockIdx.x;
    const int r0 = 2 * t, r1 = 2 * t + 1;
    int v0 = (r0 < A_NB) ? cntM[r0 * CB + b] : 0;
    int v1 = (r1 < A_NB) ? cntM[r1 * CB + b] : 0;
    s[t] = v0 + v1;
    __syncthreads();
    for (int off = 1; off < 1024; off <<= 1) {
        int u = (t >= off) ? s[t - off] : 0;
        __syncthreads();
        s[t] += u;
        __syncthreads();
    }
    int base0 = s[t] - v0 - v1;                 // exclusive prefix before pair
    if (r0 < A_NB) exclM[r0 * CB + b] = base0;
    if (r1 < A_NB) exclM[r1 * CB + b] = base0 + v0;
    if (t == 1023) btot[b] = s[1023];
}

// ---- S2: exclusive scan of bucket totals -> bucket bases ----
__global__ __launch_bounds__(1024) void scanS2_kernel(
    const int* __restrict__ btot, int* __restrict__ bbase, int* __restrict__ row_ptr)
{
    __shared__ int s[1024];
    const int t = threadIdx.x;
    int v = (t < CB) ? btot[t] : 0;
    s[t] = v;
    __syncthreads();
    for (int off = 1; off < 1024; off <<= 1) {
        int u = (t >= off) ? s[t - off] : 0;
        __syncthreads();
        s[t] += u;
        __syncthreads();
    }
    if (t < CB) bbase[t] = s[t] - v;
    if (t == 0) row_ptr[N_NODES] = N_EDGES;
}

// ---- A3: coarse scatter (zero global atomics), SoA 20B/edge ----
// ea_tmp: f16x8 edge attrs (16B); sd_tmp: src (bits 0..19) | dst&511 (bits 20..28)
__global__ __launch_bounds__(256) void scatterA_kernel(
    const int*   __restrict__ src,
    const int*   __restrict__ dst,
    const float* __restrict__ edge_attr,
    const int*   __restrict__ exclM,
    const int*   __restrict__ bbase,
    uint4*       __restrict__ ea_tmp,
    uint*        __restrict__ sd_tmp)
{
    __shared__ int cur[CB];
    const int t = threadIdx.x;
    for (int i = t; i < CB; i += 256)
        cur[i] = bbase[i] + exclM[blockIdx.x * CB + i];
    __syncthreads();
    const int e0 = blockIdx.x * A_EPB;
    const float4* ea4 = (const float4*)edge_attr;
    for (int j = 0; j < A_EPB; j += 256) {
        int e = e0 + j + t;
        if (e >= N_EDGES) continue;
        int dn = dst[e];
        int pos = atomicAdd(&cur[dn >> BSH], 1);
        float4 a = ea4[(long)e * 2];
        float4 c = ea4[(long)e * 2 + 1];
        ea_tmp[pos] = make_uint4(ph2(a.x, a.y), ph2(a.z, a.w),
                                 ph2(c.x, c.y), ph2(c.z, c.w));
        sd_tmp[pos] = (uint)src[e] | ((uint)(dn & (BKN - 1)) << 20);
    }
}

// ---- B: per-bucket fine scatter -> SoA {ea16, srcf} + exact row_ptr ----
// FB_SPLIT sub-blocks per bucket, split by node-ownership.
__global__ __launch_bounds__(512) void fineB_kernel(
    const uint4* __restrict__ ea_tmp,
    const uint*  __restrict__ sd_tmp,
    const int*   __restrict__ bbase,
    int*         __restrict__ row_ptr,
    uint4*       __restrict__ ea16,
    int*         __restrict__ srcf)
{
    __shared__ int h[BKN];
    __shared__ int ex[BKN];
    const int t = threadIdx.x;
    const int b = blockIdx.x / FB_SPLIT;          // bucket
    const int s = blockIdx.x % FB_SPLIT;          // owned half: nl>>8 == s
    const int e0 = bbase[b];
    const int e1 = (b == CB - 1) ? N_EDGES : bbase[b + 1];

    h[t] = 0;
    __syncthreads();
    for (int r = e0 + t; r < e1; r += 512)
        atomicAdd(&h[sd_tmp[r] >> 20], 1);
    __syncthreads();
    ex[t] = h[t];
    __syncthreads();
    for (int off = 1; off < BKN; off <<= 1) {
        int u = (t >= off) ? ex[t - off] : 0;
        __syncthreads();
        ex[t] += u;
        __syncthreads();
    }
    {
        int excl = ex[t] - h[t];
        int n = b * BKN + t;
        if (s == 0 && n < N_NODES) row_ptr[n] = e0 + excl;
        h[t] = e0 + excl;
    }
    __syncthreads();
    for (int r = e0 + t; r < e1; r += 512) {
        uint sd = sd_tmp[r];
        int nl = (int)(sd >> 20);
        if ((nl >> 8) == s) {                     // owned node -> place it
            uint4 ea = ea_tmp[r];
            int pos = atomicAdd(&h[nl], 1);
            ea16[pos] = ea;
            srcf[pos] = (int)(sd & 0xFFFFFu);
        }
    }
}

// ---------------- GINE layer, restructured (r10) ----------------
// EDGE PASS: each halfwave owns a FIXED 128-edge segment of the CSR edge
// array. Uniform 32-iteration loops (no per-node trip-count divergence),
// deep pipelining, no LDS (24 waves/CU). Partial per-node sums flushed to a
// zeroed global f32 agg via atomicAdd at node boundaries (~9 flushes/seg).
__global__ __launch_bounds__(256) void gine_edge_pass(
    const ushort* __restrict__ xb_in,
    float* __restrict__ agg,
    const int* __restrict__ row_ptr,
    const uint4* __restrict__ ea16,
    const int* __restrict__ srcf,
    const float* __restrict__ We,
    const float* __restrict__ be)
{
    const int t = threadIdx.x;
    const int d = t & 31;

    half2v wep[4];
#pragma unroll
    for (int k = 0; k < 4; ++k) {
        wep[k].x = (__fp16)We[(2 * k) * D + d];
        wep[k].y = (__fp16)We[(2 * k + 1) * D + d];
    }
    const float bed = be[d];

    const int hw = blockIdx.x * 8 + (t >> 5);
    const int s0 = hw * SEG;
    if (s0 >= N_EDGES) return;
    const int s1 = (s0 + SEG < N_EDGES) ? (s0 + SEG) : N_EDGES;

    // binary search: n with row_ptr[n] <= s0 < row_ptr[n+1]
    int lo = 0, hi = N_NODES;
    while (hi - lo > 1) {
        int mid = (lo + hi) >> 1;
        if (row_ptr[mid] <= s0) lo = mid; else hi = mid;
    }
    int n = lo;
    int nend = row_ptr[n + 1];

    float acc = 0.0f;
    for (int base = s0; base < s1; base += 4) {
        uint4 ev[4];
        int sj[4];
#pragma unroll
        for (int j = 0; j < 4; ++j) {
            int idx = base + j; idx = (idx < s1) ? idx : (s1 - 1);
            ev[j] = ea16[idx];       // 16B, halfwave-uniform addr -> broadcast
            sj[j] = srcf[idx];
        }
        float xv[4];
#pragma unroll
        for (int j = 0; j < 4; ++j)
            xv[j] = bf_us(xb_in[sj[j] * D + d]);
#pragma unroll
        for (int j = 0; j < 4; ++j) {
            int e = base + j;
            if (e < s1) {
                while (e >= nend) {              // crossed node boundary
                    if (acc != 0.0f) atomicAdd(&agg[(long)n * D + d], acc);
                    acc = 0.0f;
                    ++n;
                    nend = row_ptr[n + 1];       // handles empty nodes (repeat)
                }
                float ee = fdot2f(ev[j].w, wep[3],
                           fdot2f(ev[j].z, wep[2],
                           fdot2f(ev[j].y, wep[1],
                           fdot2f(ev[j].x, wep[0], bed))));
                acc += fmaxf(xv[j] + ee, 0.0f);
            }
        }
    }
    if (acc != 0.0f) atomicAdd(&agg[(long)n * D + d], acc);   // trailing partial
}

// NODE PASS: h = x + agg; re-zero agg for next layer; W matmul; leaky-relu.
__global__ __launch_bounds__(256) void gine_node_pass(
    const ushort* __restrict__ xb_in, ushort* __restrict__ xb_out,
    float* __restrict__ f32_out, float* __restrict__ agg,
    const float* __restrict__ W, const float* __restrict__ b)
{
    __shared__ float W_s[D * D];
    const int t = threadIdx.x;
    for (int i = t; i < D * D; i += 256) W_s[i] = W[i];
    const int n = blockIdx.x * 8 + (t >> 5);
    const int d = t & 31;
    const float bd = b[d];
    __syncthreads();
    if (n >= N_NODES) return;
    const long off = (long)n * D + d;
    float h = bf_us(xb_in[off]) + agg[off];
    agg[off] = 0.0f;                              // ready for next layer
    float o = bd;
#pragma unroll
    for (int k = 0; k < D; ++k)
        o += __shfl(h, k, 32) * W_s[k * D + d];
    o = o > 0.0f ? o : NEG_SLOPE * o;
    xb_out[off] = (ushort)bf16_rne(o);
    if (f32_out) f32_out[off] = o;
}

// =================== mid-tier (r5 CSR build + bf16 layer) ===================
__global__ __launch_bounds__(256) void hist_kernel(
    const int* __restrict__ dst, int* __restrict__ deg)
{
    int i = blockIdx.x * 256 + threadIdx.x;
    if (i >= N_EDGES / 4) return;
    int4 dd = ((const int4*)dst)[i];
    atomicAdd(&deg[dd.x], 1);
    atomicAdd(&deg[dd.y], 1);
    atomicAdd(&deg[dd.z], 1);
    atomicAdd(&deg[dd.w], 1);
}

__global__ __launch_bounds__(1024) void scan_phase1(
    const int* __restrict__ deg, int* __restrict__ bsums)
{
    __shared__ int s[1024];
    int t = threadIdx.x;
    int i = blockIdx.x * 1024 + t;
    s[t] = (i < N_NODES) ? deg[i] : 0;
    __syncthreads();
    for (int off = 512; off > 0; off >>= 1) {
        if (t < off) s[t] += s[t + off];
        __syncthreads();
    }
    if (t == 0) bsums[blockIdx.x] = s[0];
}

__global__ __launch_bounds__(128) void scan_phase2(int* __restrict__ bsums)
{
    __shared__ int s[128];
    int t = threadIdx.x;
    int v = (t < NBLK) ? bsums[t] : 0;
    s[t] = v;
    __syncthreads();
    for (int off = 1; off < 128; off <<= 1) {
        int u = (t >= off) ? s[t - off] : 0;
        __syncthreads();
        s[t] += u;
        __syncthreads();
    }
    if (t < NBLK) bsums[t] = s[t] - v;
}

__global__ __launch_bounds__(1024) void scan_phase3(
    const int* __restrict__ deg, const int* __restrict__ bsums,
    int* __restrict__ row_ptr, int* __restrict__ offs)
{
    __shared__ int s[1024];
    int t = threadIdx.x;
    int i = blockIdx.x * 1024 + t;
    int v = (i < N_NODES) ? deg[i] : 0;
    s[t] = v;
    __syncthreads();
    for (int off = 1; off < 1024; off <<= 1) {
        int u = (t >= off) ? s[t - off] : 0;
        __syncthreads();
        s[t] += u;
        __syncthreads();
    }
    int excl = bsums[blockIdx.x] + s[t] - v;
    if (i < N_NODES) { row_ptr[i] = excl; offs[i] = excl; }
    else if (i == N_NODES) row_ptr[i] = excl;
}

__global__ __launch_bounds__(256) void scatter_rec_kernel(
    const int* __restrict__ src, const int* __restrict__ dst,
    const float* __restrict__ edge_attr, int* __restrict__ offs,
    uint* __restrict__ rec)
{
    int e = blockIdx.x * 256 + threadIdx.x;
    if (e >= N_EDGES) return;
    int pos = atomicAdd(&offs[dst[e]], 1);
    const float4* ea4 = (const float4*)edge_attr;
    float4 a = ea4[(long)e * 2];
    float4 c = ea4[(long)e * 2 + 1];
    uint* r = rec + (long)pos * 8;
    *(uint4*)r = make_uint4((uint)src[e], pack2(a.x, a.y), pack2(a.z, a.w), pack2(c.x, c.y));
    r[4] = pack2(c.z, c.w);
}

__global__ __launch_bounds__(256) void gine_fused2_kernel(
    const ushort* __restrict__ xb_in, ushort* __restrict__ xb_out,
    float* __restrict__ f32_out, const int* __restrict__ row_ptr,
    const uint* __restrict__ rec,
    const float* __restrict__ W, const float* __restrict__ b,
    const float* __restrict__ We, const float* __restrict__ be)
{
    __shared__ float W_s[D * D];
    __shared__ float We_s[ED * D];
    __shared__ float b_s[D];
    __shared__ float be_s[D];
    const int t = threadIdx.x;
    for (int i = t; i < D * D; i += 256) W_s[i] = W[i];
    if (t < ED * D) We_s[t] = We[t];
    if (t < D) { b_s[t] = b[t]; be_s[t] = be[t]; }
    __syncthreads();
    const int n = blockIdx.x * 8 + (t >> 5);
    const int d = t & 31;
    if (n >= N_NODES) return;
    float wer[ED];
#pragma unroll
    for (int k = 0; k < ED; ++k) wer[k] = We_s[k * D + d];
    const float bed = be_s[d];
    const int row = row_ptr[n], rend = row_ptr[n + 1];
    float selfx = bf_us(xb_in[n * D + d]);
    float acc = 0.0f;
    for (int pos = row; pos < rend; pos += 8) {
        const int rem = rend - pos;
        const uint2* rp = (const uint2*)(rec + (long)pos * 8);
        uint2 v = rp[d];
        int srcs[8];
#pragma unroll
        for (int j = 0; j < 8; ++j) srcs[j] = __shfl((int)v.x, 4 * j, 32);
        const int s0 = srcs[0];
        float xv[8];
#pragma unroll
        for (int j = 0; j < 8; ++j) {
            int sj = (j < rem) ? srcs[j] : s0;
            xv[j] = bf_us(xb_in[sj * D + d]);
        }
#pragma unroll
        for (int j = 0; j < 8; ++j) {
            uint u01 = (uint)__shfl((int)v.y, 4 * j, 32);
            uint u23 = (uint)__shfl((int)v.x, 4 * j + 1, 32);
            uint u45 = (uint)__shfl((int)v.y, 4 * j + 1, 32);
            uint u67 = (uint)__shfl((int)v.x, 4 * j + 2, 32);
            float e = bed;
            e += bf_lo(u01) * wer[0]; e += bf_hi(u01) * wer[1];
            e += bf_lo(u23) * wer[2]; e += bf_hi(u23) * wer[3];
            e += bf_lo(u45) * wer[4]; e += bf_hi(u45) * wer[5];
            e += bf_lo(u67) * wer[6]; e += bf_hi(u67) * wer[7];
            float msg = fmaxf(xv[j] + e, 0.0f);
            acc += (j < rem) ? msg : 0.0f;
        }
    }
    float h = selfx + acc;
    float o = b_s[d];
#pragma unroll
    for (int k = 0; k < D; ++k)
        o += __shfl(h, k, 32) * W_s[k * D + d];
    o = o > 0.0f ? o : NEG_SLOPE * o;
    xb_out[n * D + d] = (ushort)bf16_rne(o);
    if (f32_out) f32_out[n * D + d] = o;
}

// =================== round-1 fallback ===================
__global__ __launch_bounds__(256) void gine_edge_kernel(
    const float* __restrict__ x, const float* __restrict__ edge_attr,
    const float* __restrict__ We, const float* __restrict__ be,
    const int* __restrict__ src, const int* __restrict__ dst,
    float* __restrict__ agg)
{
    __shared__ float We_s[ED * D];
    __shared__ float be_s[D];
    int t = threadIdx.x;
    if (t < ED * D) We_s[t] = We[t];
    if (t < D) be_s[t] = be[t];
    __syncthreads();
    long gtid = (long)blockIdx.x * blockDim.x + t;
    int e = (int)(gtid >> 5), d = (int)(gtid & 31);
    if (e >= N_EDGES) return;
    int s = src[e], dn = dst[e];
    float acc = be_s[d];
#pragma unroll
    for (int k = 0; k < ED; ++k)
        acc += edge_attr[(long)e * ED + k] * We_s[k * D + d];
    float m = fmaxf(x[(long)s * D + d] + acc, 0.0f);
    atomicAdd(&agg[(long)dn * D + d], m);
}

__global__ __launch_bounds__(256) void gine_node_kernel(
    float* __restrict__ x, const float* __restrict__ agg,
    const float* __restrict__ W, const float* __restrict__ b)
{
    __shared__ float W_s[D * D];
    __shared__ float b_s[D];
    int t = threadIdx.x;
    for (int i = t; i < D * D; i += 256) W_s[i] = W[i];
    if (t < D) b_s[t] = b[t];
    __syncthreads();
    long gtid = (long)blockIdx.x * blockDim.x + t;
    int n = (int)(gtid >> 5), d = (int)(gtid & 31);
    if (n >= N_NODES) return;
    float h = x[(long)n * D + d] + agg[(long)n * D + d];
    float acc = b_s[d];
#pragma unroll
    for (int k = 0; k < D; ++k)
        acc += __shfl(h, k, D) * W_s[k * D + d];
    x[(long)n * D + d] = acc > 0.0f ? acc : NEG_SLOPE * acc;
}

// =================== launch ===================
extern "C" void kernel_launch(void* const* d_in, const int* in_sizes, int n_in,
                              void* d_out, int out_size, void* d_ws, size_t ws_size,
                              hipStream_t stream) {
    const float* x_in      = (const float*)d_in[0];
    const float* edge_attr = (const float*)d_in[1];
    const float* W         = (const float*)d_in[2];
    const float* b         = (const float*)d_in[3];
    const float* We        = (const float*)d_in[4];
    const float* be        = (const float*)d_in[5];
    const int*   ei        = (const int*)d_in[6];
    const int* src = ei;
    const int* dst = ei + N_EDGES;

    const size_t xbytes  = (size_t)N_NODES * D * sizeof(float);
    const size_t xbbytes = (size_t)N_NODES * D * sizeof(ushort);  // 6.4 MB
    const size_t aggbytes = (size_t)N_NODES * D * sizeof(float);  // 12.8 MB

    auto align = [](size_t v) { return (v + 255) & ~(size_t)255; };
    size_t off_xba  = 0;
    size_t off_rp   = align(off_xba + xbbytes);                    // row_ptr N+1
    size_t off_cnt  = align(off_rp + (N_NODES + 1) * sizeof(int)); // cntM / deg
    size_t off_excl = align(off_cnt + (size_t)A_NB * CB * sizeof(int));  // exclM / offs
    size_t off_bt   = align(off_excl + (size_t)A_NB * CB * sizeof(int)); // btot / bsums
    size_t off_bb   = align(off_bt + CB * sizeof(int));            // bbase
    size_t off_ea   = align(off_bb + CB * sizeof(int));            // ea16 (E+8)*16B
    size_t off_src  = align(off_ea + ((size_t)N_EDGES + 8) * 16);  // srcf (E+8)*4B
    size_t off_eat  = align(off_src + ((size_t)N_EDGES + 8) * 4);  // ea_tmp E*16B / xbB+agg
    size_t off_sdt  = align(off_eat + ((size_t)N_EDGES + 8) * 16); // sd_tmp E*4B
    size_t need_big = off_sdt + ((size_t)N_EDGES + 8) * 4 + 256;
    // xbB and agg alias ea_tmp (dead after fineB): xbB at +0, agg at +xbbytes.
    size_t off_agg  = align(off_eat + xbbytes);
    // mid tier: rec (E*32B) at off_ea, xbB after
    size_t off_mrec = off_ea;
    size_t off_mxbb = align(off_mrec + ((size_t)N_EDGES + 8) * 32);
    size_t need_mid = off_mxbb + xbbytes + 256;

    char* ws = (char*)d_ws;
    ushort* xbA    = (ushort*)(ws + off_xba);
    int*   row_ptr = (int*)   (ws + off_rp);
    int*   cntM    = (int*)   (ws + off_cnt);
    int*   exclM   = (int*)   (ws + off_excl);
    int*   btot    = (int*)   (ws + off_bt);
    int*   bbase   = (int*)   (ws + off_bb);
    uint4* ea16    = (uint4*) (ws + off_ea);
    int*   srcf    = (int*)   (ws + off_src);
    uint4* ea_tmp  = (uint4*) (ws + off_eat);
    uint*  sd_tmp  = (uint*)  (ws + off_sdt);
    ushort* xbB    = (ushort*)(ws + off_eat);   // aliases ea_tmp (dead after fineB)
    float* agg     = (float*) (ws + off_agg);   // aliases ea_tmp+6.4MB (dead)
    float* xout    = (float*)d_out;

    if (ws_size >= need_big) {
        pack_x_kernel<<<(N_NODES * D / 4 + 255) / 256, 256, 0, stream>>>(x_in, xbA);
        countA_kernel<<<A_NB, 256, 0, stream>>>(dst, cntM);
        scanS1_kernel<<<CB, 1024, 0, stream>>>(cntM, exclM, btot);
        scanS2_kernel<<<1, 1024, 0, stream>>>(btot, bbase, row_ptr);
        scatterA_kernel<<<A_NB, 256, 0, stream>>>(src, dst, edge_attr, exclM, bbase,
                                                  ea_tmp, sd_tmp);
        fineB_kernel<<<CB * FB_SPLIT, 512, 0, stream>>>(ea_tmp, sd_tmp, bbase, row_ptr,
                                                        ea16, srcf);
        hipMemsetAsync(agg, 0, aggbytes, stream);   // after fineB (agg aliases ea_tmp)

        const int EGRID = (N_EDGES / SEG + 7) / 8;          // 1563
        dim3 blk(256), ngrid((N_NODES + 7) / 8);
        gine_edge_pass<<<EGRID, blk, 0, stream>>>(xbA, agg, row_ptr, ea16, srcf, We, be);
        gine_node_pass<<<ngrid, blk, 0, stream>>>(xbA, xbB, nullptr, agg, W, b);
        gine_edge_pass<<<EGRID, blk, 0, stream>>>(xbB, agg, row_ptr, ea16, srcf,
            We + ED * D, be + D);
        gine_node_pass<<<ngrid, blk, 0, stream>>>(xbB, xbA, nullptr, agg,
            W + D * D, b + D);
        gine_edge_pass<<<EGRID, blk, 0, stream>>>(xbA, agg, row_ptr, ea16, srcf,
            We + 2 * ED * D, be + 2 * D);
        gine_node_pass<<<ngrid, blk, 0, stream>>>(xbA, xbB, xout, agg,
            W + 2 * D * D, b + 2 * D);
    } else if (ws_size >= need_mid) {
        int* deg  = cntM;
        int* offs = exclM;
        int* bsums = btot;
        uint* rec = (uint*)(ws + off_mrec);
        ushort* xbBm = (ushort*)(ws + off_mxbb);
        pack_x_kernel<<<(N_NODES * D / 4 + 255) / 256, 256, 0, stream>>>(x_in, xbA);
        hipMemsetAsync(deg, 0, N_NODES * sizeof(int), stream);
        hist_kernel<<<(N_EDGES / 4 + 255) / 256, 256, 0, stream>>>(dst, deg);
        scan_phase1<<<NBLK, 1024, 0, stream>>>(deg, bsums);
        scan_phase2<<<1, 128, 0, stream>>>(bsums);
        scan_phase3<<<NBLK, 1024, 0, stream>>>(deg, bsums, row_ptr, offs);
        scatter_rec_kernel<<<(N_EDGES + 255) / 256, 256, 0, stream>>>(
            src, dst, edge_attr, offs, rec);
        dim3 blk(256), grid((N_NODES + 7) / 8);
        gine_fused2_kernel<<<grid, blk, 0, stream>>>(xbA, xbBm, nullptr, row_ptr, rec,
            W, b, We, be);
        gine_fused2_kernel<<<grid, blk, 0, stream>>>(xbBm, xbA, nullptr, row_ptr, rec,
            W + D * D, b + D, We + ED * D, be + D);
        gine_fused2_kernel<<<grid, blk, 0, stream>>>(xbA, xbBm, xout, row_ptr, rec,
            W + 2 * D * D, b + 2 * D, We + 2 * ED * D, be + 2 * D);
    } else {
        float* x = (float*)d_out;
        float* agg2 = (float*)d_ws;
        hipMemcpyAsync(x, x_in, xbytes, hipMemcpyDeviceToDevice, stream);
        dim3 eblk(256), egrid(((long)N_EDGES * D + 255) / 256);
        dim3 nblk(256), ngrid2(((long)N_NODES * D + 255) / 256);
        for (int l = 0; l < 3; ++l) {
            hipMemsetAsync(agg2, 0, xbytes, stream);
            gine_edge_kernel<<<egrid, eblk, 0, stream>>>(
                x, edge_attr, We + (size_t)l * ED * D, be + (size_t)l * D, src, dst, agg2);
            gine_node_kernel<<<ngrid2, nblk, 0, stream>>>(
                x, agg2, W + (size_t)l * D * D, b + (size_t)l * D);
        }
    }
}

// Round 12
// 457.254 us; speedup vs baseline: 1.0471x; 1.0471x over previous
//
#include <hip/hip_runtime.h>

#define N_NODES 100000
#define N_EDGES 1600000
#define D 32
#define ED 8
#define NEG_SLOPE 0.01f
#define NBLK 98                                  // scan blocks (98*1024 >= N)

typedef unsigned int uint;
typedef unsigned short ushort;
typedef __fp16 half2v __attribute__((ext_vector_type(2)));

__device__ __forceinline__ uint bf16_rne(float f) {
    uint u = __float_as_uint(f);
    return (u + 0x7fffu + ((u >> 16) & 1u)) >> 16;
}
__device__ __forceinline__ uint pack2(float lo, float hi) {
    return bf16_rne(lo) | (bf16_rne(hi) << 16);
}
__device__ __forceinline__ float bf_lo(uint u) { return __uint_as_float(u << 16); }
__device__ __forceinline__ float bf_hi(uint u) { return __uint_as_float(u & 0xffff0000u); }
__device__ __forceinline__ float bf_us(ushort u) { return __uint_as_float(((uint)u) << 16); }

// pack two floats -> f16x2 (RNE)
__device__ __forceinline__ uint ph2(float lo, float hi) {
    __fp16 l = (__fp16)lo, h = (__fp16)hi;
    return (uint)__builtin_bit_cast(ushort, l) | ((uint)__builtin_bit_cast(ushort, h) << 16);
}

#if defined(__has_builtin) && __has_builtin(__builtin_amdgcn_fdot2)
__device__ __forceinline__ float fdot2f(uint u, half2v w, float c) {
    return __builtin_amdgcn_fdot2(__builtin_bit_cast(half2v, u), w, c, false);
}
#else
__device__ __forceinline__ float fdot2f(uint u, half2v w, float c) {
    half2v a = __builtin_bit_cast(half2v, u);
    return c + (float)a.x * (float)w.x + (float)a.y * (float)w.y;
}
#endif

// ---------------- x -> bf16 pack ----------------
__global__ __launch_bounds__(256) void pack_x_kernel(
    const float* __restrict__ x, ushort* __restrict__ xb)
{
    int i = blockIdx.x * 256 + threadIdx.x;     // over N*D/4
    if (i >= N_NODES * D / 4) return;
    float4 f = ((const float4*)x)[i];
    ((uint2*)xb)[i] = make_uint2(pack2(f.x, f.y), pack2(f.z, f.w));
}

// ---- degree histogram (global atomics) ----
__global__ __launch_bounds__(256) void hist_kernel(
    const int* __restrict__ dst, int* __restrict__ deg)
{
    int i = blockIdx.x * 256 + threadIdx.x;
    if (i >= N_EDGES / 4) return;
    int4 dd = ((const int4*)dst)[i];
    atomicAdd(&deg[dd.x], 1);
    atomicAdd(&deg[dd.y], 1);
    atomicAdd(&deg[dd.z], 1);
    atomicAdd(&deg[dd.w], 1);
}

// ---- 3-phase exact scan: deg -> row_ptr (+offs working copy) ----
__global__ __launch_bounds__(1024) void scan_phase1(
    const int* __restrict__ deg, int* __restrict__ bsums)
{
    __shared__ int s[1024];
    int t = threadIdx.x;
    int i = blockIdx.x * 1024 + t;
    s[t] = (i < N_NODES) ? deg[i] : 0;
    __syncthreads();
    for (int off = 512; off > 0; off >>= 1) {
        if (t < off) s[t] += s[t + off];
        __syncthreads();
    }
    if (t == 0) bsums[blockIdx.x] = s[0];
}

__global__ __launch_bounds__(128) void scan_phase2(int* __restrict__ bsums)
{
    __shared__ int s[128];
    int t = threadIdx.x;
    int v = (t < NBLK) ? bsums[t] : 0;
    s[t] = v;
    __syncthreads();
    for (int off = 1; off < 128; off <<= 1) {
        int u = (t >= off) ? s[t - off] : 0;
        __syncthreads();
        s[t] += u;
        __syncthreads();
    }
    if (t < NBLK) bsums[t] = s[t] - v;
}

__global__ __launch_bounds__(1024) void scan_phase3(
    const int* __restrict__ deg, const int* __restrict__ bsums,
    int* __restrict__ row_ptr, int* __restrict__ offs)
{
    __shared__ int s[1024];
    int t = threadIdx.x;
    int i = blockIdx.x * 1024 + t;
    int v = (i < N_NODES) ? deg[i] : 0;
    s[t] = v;
    __syncthreads();
    for (int off = 1; off < 1024; off <<= 1) {
        int u = (t >= off) ? s[t - off] : 0;
        __syncthreads();
        s[t] += u;
        __syncthreads();
    }
    int excl = bsums[blockIdx.x] + s[t] - v;
    if (i < N_NODES) { row_ptr[i] = excl; offs[i] = excl; }
    else if (i == N_NODES) row_ptr[i] = excl;
}

// ---- single-pass direct scatter to final SoA {ea16, srcf} ----
// One global atomic per edge on offs[dst]; 16B+4B writes land at final CSR
// position. Replaces the old countA/scanS1/scanS2/scatterA/fineB pipeline
// (which moved the 20B payload twice).
__global__ __launch_bounds__(256) void scatter_soa_kernel(
    const int* __restrict__ src, const int* __restrict__ dst,
    const float* __restrict__ edge_attr, int* __restrict__ offs,
    uint4* __restrict__ ea16, int* __restrict__ srcf)
{
    int e = blockIdx.x * 256 + threadIdx.x;
    if (e >= N_EDGES) return;
    const float4* ea4 = (const float4*)edge_attr;
    float4 a = ea4[(long)e * 2];
    float4 c = ea4[(long)e * 2 + 1];
    int pos = atomicAdd(&offs[dst[e]], 1);
    ea16[pos] = make_uint4(ph2(a.x, a.y), ph2(a.z, a.w),
                           ph2(c.x, c.y), ph2(c.z, c.w));
    srcf[pos] = src[e];
}

// ---------------- fused GINE layer (r9-measured config, 66.5us) ----------------
// Half-wave (32 lanes) per node. Per-edge record data broadcast to the
// half-wave by SAME-ADDRESS vector loads: zero DS ops in the inner loop.
// 4-edge chunks + masked tail; plain loads (nt-loads hurt: +10MB FETCH).
__global__ __launch_bounds__(256) void gine_fused4_kernel(
    const ushort* __restrict__ xb_in, ushort* __restrict__ xb_out,
    float* __restrict__ f32_out, const int* __restrict__ row_ptr,
    const uint4* __restrict__ ea16, const int* __restrict__ srcf,
    const float* __restrict__ W, const float* __restrict__ b,
    const float* __restrict__ We, const float* __restrict__ be)
{
    __shared__ float W_s[D * D];
    const int t = threadIdx.x;
    for (int i = t; i < D * D; i += 256) W_s[i] = W[i];

    const int n = blockIdx.x * 8 + (t >> 5);
    const int d = t & 31;

    half2v wep[4];
#pragma unroll
    for (int k = 0; k < 4; ++k) {
        wep[k].x = (__fp16)We[(2 * k) * D + d];
        wep[k].y = (__fp16)We[(2 * k + 1) * D + d];
    }
    const float bed = be[d];
    const float bd  = b[d];
    __syncthreads();
    if (n >= N_NODES) return;

    const int row = row_ptr[n], rend = row_ptr[n + 1];
    float selfx = bf_us(xb_in[n * D + d]);

    float acc = 0.0f;
    int pos = row;
    // main loop: full chunks of 4 edges, no masking
    for (; pos + 4 <= rend; pos += 4) {
        uint4 ev[4];
        int sj[4];
#pragma unroll
        for (int j = 0; j < 4; ++j) {
            ev[j] = ea16[pos + j];     // 16B, half-wave-uniform addr -> broadcast
            sj[j] = srcf[pos + j];     // 4B, half-wave-uniform addr -> broadcast
        }
        float xv[4];
#pragma unroll
        for (int j = 0; j < 4; ++j)
            xv[j] = bf_us(xb_in[sj[j] * D + d]);
#pragma unroll
        for (int j = 0; j < 4; ++j) {
            float e = fdot2f(ev[j].w, wep[3],
                      fdot2f(ev[j].z, wep[2],
                      fdot2f(ev[j].y, wep[1],
                      fdot2f(ev[j].x, wep[0], bed))));
            acc += fmaxf(xv[j] + e, 0.0f);
        }
    }
    // tail chunk (1..3 edges), masked
    if (pos < rend) {
        const int rem = rend - pos;
        uint4 ev[4];
        int sj[4];
#pragma unroll
        for (int j = 0; j < 4; ++j) {
            int idx = pos + ((j < rem) ? j : 0);   // clamp: always in-bounds
            ev[j] = ea16[idx];
            sj[j] = srcf[idx];
        }
        float xv[4];
#pragma unroll
        for (int j = 0; j < 4; ++j)
            xv[j] = bf_us(xb_in[sj[j] * D + d]);
#pragma unroll
        for (int j = 0; j < 4; ++j) {
            float e = fdot2f(ev[j].w, wep[3],
                      fdot2f(ev[j].z, wep[2],
                      fdot2f(ev[j].y, wep[1],
                      fdot2f(ev[j].x, wep[0], bed))));
            float msg = fmaxf(xv[j] + e, 0.0f);
            acc += (j < rem) ? msg : 0.0f;
        }
    }

    float h = selfx + acc;
    float o = bd;
#pragma unroll
    for (int k = 0; k < D; ++k)
        o += __shfl(h, k, 32) * W_s[k * D + d];
    o = o > 0.0f ? o : NEG_SLOPE * o;
    xb_out[n * D + d] = (ushort)bf16_rne(o);
    if (f32_out) f32_out[n * D + d] = o;
}

// =================== mid-tier (AoS rec build + bf16 layer) ===================
__global__ __launch_bounds__(256) void scatter_rec_kernel(
    const int* __restrict__ src, const int* __restrict__ dst,
    const float* __restrict__ edge_attr, int* __restrict__ offs,
    uint* __restrict__ rec)
{
    int e = blockIdx.x * 256 + threadIdx.x;
    if (e >= N_EDGES) return;
    int pos = atomicAdd(&offs[dst[e]], 1);
    const float4* ea4 = (const float4*)edge_attr;
    float4 a = ea4[(long)e * 2];
    float4 c = ea4[(long)e * 2 + 1];
    uint* r = rec + (long)pos * 8;
    *(uint4*)r = make_uint4((uint)src[e], pack2(a.x, a.y), pack2(a.z, a.w), pack2(c.x, c.y));
    r[4] = pack2(c.z, c.w);
}

__global__ __launch_bounds__(256) void gine_fused2_kernel(
    const ushort* __restrict__ xb_in, ushort* __restrict__ xb_out,
    float* __restrict__ f32_out, const int* __restrict__ row_ptr,
    const uint* __restrict__ rec,
    const float* __restrict__ W, const float* __restrict__ b,
    const float* __restrict__ We, const float* __restrict__ be)
{
    __shared__ float W_s[D * D];
    __shared__ float We_s[ED * D];
    __shared__ float b_s[D];
    __shared__ float be_s[D];
    const int t = threadIdx.x;
    for (int i = t; i < D * D; i += 256) W_s[i] = W[i];
    if (t < ED * D) We_s[t] = We[t];
    if (t < D) { b_s[t] = b[t]; be_s[t] = be[t]; }
    __syncthreads();
    const int n = blockIdx.x * 8 + (t >> 5);
    const int d = t & 31;
    if (n >= N_NODES) return;
    float wer[ED];
#pragma unroll
    for (int k = 0; k < ED; ++k) wer[k] = We_s[k * D + d];
    const float bed = be_s[d];
    const int row = row_ptr[n], rend = row_ptr[n + 1];
    float selfx = bf_us(xb_in[n * D + d]);
    float acc = 0.0f;
    for (int pos = row; pos < rend; pos += 8) {
        const int rem = rend - pos;
        const uint2* rp = (const uint2*)(rec + (long)pos * 8);
        uint2 v = rp[d];
        int srcs[8];
#pragma unroll
        for (int j = 0; j < 8; ++j) srcs[j] = __shfl((int)v.x, 4 * j, 32);
        const int s0 = srcs[0];
        float xv[8];
#pragma unroll
        for (int j = 0; j < 8; ++j) {
            int sj = (j < rem) ? srcs[j] : s0;
            xv[j] = bf_us(xb_in[sj * D + d]);
        }
#pragma unroll
        for (int j = 0; j < 8; ++j) {
            uint u01 = (uint)__shfl((int)v.y, 4 * j, 32);
            uint u23 = (uint)__shfl((int)v.x, 4 * j + 1, 32);
            uint u45 = (uint)__shfl((int)v.y, 4 * j + 1, 32);
            uint u67 = (uint)__shfl((int)v.x, 4 * j + 2, 32);
            float e = bed;
            e += bf_lo(u01) * wer[0]; e += bf_hi(u01) * wer[1];
            e += bf_lo(u23) * wer[2]; e += bf_hi(u23) * wer[3];
            e += bf_lo(u45) * wer[4]; e += bf_hi(u45) * wer[5];
            e += bf_lo(u67) * wer[6]; e += bf_hi(u67) * wer[7];
            float msg = fmaxf(xv[j] + e, 0.0f);
            acc += (j < rem) ? msg : 0.0f;
        }
    }
    float h = selfx + acc;
    float o = b_s[d];
#pragma unroll
    for (int k = 0; k < D; ++k)
        o += __shfl(h, k, 32) * W_s[k * D + d];
    o = o > 0.0f ? o : NEG_SLOPE * o;
    xb_out[n * D + d] = (ushort)bf16_rne(o);
    if (f32_out) f32_out[n * D + d] = o;
}

// =================== round-1 fallback ===================
__global__ __launch_bounds__(256) void gine_edge_kernel(
    const float* __restrict__ x, const float* __restrict__ edge_attr,
    const float* __restrict__ We, const float* __restrict__ be,
    const int* __restrict__ src, const int* __restrict__ dst,
    float* __restrict__ agg)
{
    __shared__ float We_s[ED * D];
    __shared__ float be_s[D];
    int t = threadIdx.x;
    if (t < ED * D) We_s[t] = We[t];
    if (t < D) be_s[t] = be[t];
    __syncthreads();
    long gtid = (long)blockIdx.x * blockDim.x + t;
    int e = (int)(gtid >> 5), d = (int)(gtid & 31);
    if (e >= N_EDGES) return;
    int s = src[e], dn = dst[e];
    float acc = be_s[d];
#pragma unroll
    for (int k = 0; k < ED; ++k)
        acc += edge_attr[(long)e * ED + k] * We_s[k * D + d];
    float m = fmaxf(x[(long)s * D + d] + acc, 0.0f);
    atomicAdd(&agg[(long)dn * D + d], m);
}

__global__ __launch_bounds__(256) void gine_node_kernel(
    float* __restrict__ x, const float* __restrict__ agg,
    const float* __restrict__ W, const float* __restrict__ b)
{
    __shared__ float W_s[D * D];
    __shared__ float b_s[D];
    int t = threadIdx.x;
    for (int i = t; i < D * D; i += 256) W_s[i] = W[i];
    if (t < D) b_s[t] = b[t];
    __syncthreads();
    long gtid = (long)blockIdx.x * blockDim.x + t;
    int n = (int)(gtid >> 5), d = (int)(gtid & 31);
    if (n >= N_NODES) return;
    float h = x[(long)n * D + d] + agg[(long)n * D + d];
    float acc = b_s[d];
#pragma unroll
    for (int k = 0; k < D; ++k)
        acc += __shfl(h, k, D) * W_s[k * D + d];
    x[(long)n * D + d] = acc > 0.0f ? acc : NEG_SLOPE * acc;
}

// =================== launch ===================
extern "C" void kernel_launch(void* const* d_in, const int* in_sizes, int n_in,
                              void* d_out, int out_size, void* d_ws, size_t ws_size,
                              hipStream_t stream) {
    const float* x_in      = (const float*)d_in[0];
    const float* edge_attr = (const float*)d_in[1];
    const float* W         = (const float*)d_in[2];
    const float* b         = (const float*)d_in[3];
    const float* We        = (const float*)d_in[4];
    const float* be        = (const float*)d_in[5];
    const int*   ei        = (const int*)d_in[6];
    const int* src = ei;
    const int* dst = ei + N_EDGES;

    const size_t xbytes  = (size_t)N_NODES * D * sizeof(float);
    const size_t xbbytes = (size_t)N_NODES * D * sizeof(ushort);  // 6.4 MB

    auto align = [](size_t v) { return (v + 255) & ~(size_t)255; };
    // big tier layout: one-pass CSR build, SoA records
    size_t off_xba  = 0;
    size_t off_xbb  = align(off_xba + xbbytes);                    // xbB (dedicated)
    size_t off_rp   = align(off_xbb + xbbytes);                    // row_ptr N+1
    size_t off_deg  = align(off_rp + (N_NODES + 1) * sizeof(int)); // deg
    size_t off_offs = align(off_deg + N_NODES * sizeof(int));      // offs (working)
    size_t off_bs   = align(off_offs + N_NODES * sizeof(int));     // bsums
    size_t off_ea   = align(off_bs + 1024 * sizeof(int));          // ea16 (E+8)*16B
    size_t off_src  = align(off_ea + ((size_t)N_EDGES + 8) * 16);  // srcf (E+8)*4B
    size_t need_big = off_src + ((size_t)N_EDGES + 8) * 4 + 256;
    // mid tier: rec (E*32B) at off_ea, xbB reuses off_xbb
    size_t off_mrec = off_ea;
    size_t need_mid = align(off_mrec + ((size_t)N_EDGES + 8) * 32) + 256;

    char* ws = (char*)d_ws;
    ushort* xbA    = (ushort*)(ws + off_xba);
    ushort* xbB    = (ushort*)(ws + off_xbb);
    int*   row_ptr = (int*)   (ws + off_rp);
    int*   deg     = (int*)   (ws + off_deg);
    int*   offs    = (int*)   (ws + off_offs);
    int*   bsums   = (int*)   (ws + off_bs);
    uint4* ea16    = (uint4*) (ws + off_ea);
    int*   srcf    = (int*)   (ws + off_src);
    float* xout    = (float*)d_out;

    if (ws_size >= need_big) {
        pack_x_kernel<<<(N_NODES * D / 4 + 255) / 256, 256, 0, stream>>>(x_in, xbA);
        hipMemsetAsync(deg, 0, N_NODES * sizeof(int), stream);
        hist_kernel<<<(N_EDGES / 4 + 255) / 256, 256, 0, stream>>>(dst, deg);
        scan_phase1<<<NBLK, 1024, 0, stream>>>(deg, bsums);
        scan_phase2<<<1, 128, 0, stream>>>(bsums);
        scan_phase3<<<NBLK, 1024, 0, stream>>>(deg, bsums, row_ptr, offs);
        scatter_soa_kernel<<<(N_EDGES + 255) / 256, 256, 0, stream>>>(
            src, dst, edge_attr, offs, ea16, srcf);

        dim3 blk(256), grid((N_NODES + 7) / 8);
        gine_fused4_kernel<<<grid, blk, 0, stream>>>(xbA, xbB, nullptr, row_ptr, ea16, srcf,
            W, b, We, be);
        gine_fused4_kernel<<<grid, blk, 0, stream>>>(xbB, xbA, nullptr, row_ptr, ea16, srcf,
            W + D * D, b + D, We + ED * D, be + D);
        gine_fused4_kernel<<<grid, blk, 0, stream>>>(xbA, xbB, xout, row_ptr, ea16, srcf,
            W + 2 * D * D, b + 2 * D, We + 2 * ED * D, be + 2 * D);
    } else if (ws_size >= need_mid) {
        uint* rec = (uint*)(ws + off_mrec);
        pack_x_kernel<<<(N_NODES * D / 4 + 255) / 256, 256, 0, stream>>>(x_in, xbA);
        hipMemsetAsync(deg, 0, N_NODES * sizeof(int), stream);
        hist_kernel<<<(N_EDGES / 4 + 255) / 256, 256, 0, stream>>>(dst, deg);
        scan_phase1<<<NBLK, 1024, 0, stream>>>(deg, bsums);
        scan_phase2<<<1, 128, 0, stream>>>(bsums);
        scan_phase3<<<NBLK, 1024, 0, stream>>>(deg, bsums, row_ptr, offs);
        scatter_rec_kernel<<<(N_EDGES + 255) / 256, 256, 0, stream>>>(
            src, dst, edge_attr, offs, rec);
        dim3 blk(256), grid((N_NODES + 7) / 8);
        gine_fused2_kernel<<<grid, blk, 0, stream>>>(xbA, xbB, nullptr, row_ptr, rec,
            W, b, We, be);
        gine_fused2_kernel<<<grid, blk, 0, stream>>>(xbB, xbA, nullptr, row_ptr, rec,
            W + D * D, b + D, We + ED * D, be + D);
        gine_fused2_kernel<<<grid, blk, 0, stream>>>(xbA, xbB, xout, row_ptr, rec,
            W + 2 * D * D, b + 2 * D, We + 2 * ED * D, be + 2 * D);
    } else {
        float* x = (float*)d_out;
        float* agg = (float*)d_ws;
        hipMemcpyAsync(x, x_in, xbytes, hipMemcpyDeviceToDevice, stream);
        dim3 eblk(256), egrid(((long)N_EDGES * D + 255) / 256);
        dim3 nblk(256), ngrid(((long)N_NODES * D + 255) / 256);
        for (int l = 0; l < 3; ++l) {
            hipMemsetAsync(agg, 0, xbytes, stream);
            gine_edge_kernel<<<egrid, eblk, 0, stream>>>(
                x, edge_attr, We + (size_t)l * ED * D, be + (size_t)l * D, src, dst, agg);
            gine_node_kernel<<<ngrid, nblk, 0, stream>>>(
                x, agg, W + (size_t)l * D * D, b + (size_t)l * D);
        }
    }
}

// Round 13
// 385.303 us; speedup vs baseline: 1.2426x; 1.1867x over previous
//
#include <hip/hip_runtime.h>

#define N_NODES 100000
#define N_EDGES 1600000
#define D 32
#define ED 8
#define NEG_SLOPE 0.01f
#define BSH 9                                    // bucket shift: 512 nodes/bucket
#define BKN 512                                  // nodes per bucket
#define CB ((N_NODES + BKN - 1) / BKN)           // 196 coarse buckets
#define FB_SPLIT 2                               // fineB sub-blocks per bucket
#define A_EPB 1024                               // edges per A-block
#define A_NB ((N_EDGES + A_EPB - 1) / A_EPB)     // 1563
#define NBLK 98                                  // mid-tier scan blocks

typedef unsigned int uint;
typedef unsigned short ushort;
typedef __fp16 half2v __attribute__((ext_vector_type(2)));

__device__ __forceinline__ uint bf16_rne(float f) {
    uint u = __float_as_uint(f);
    return (u + 0x7fffu + ((u >> 16) & 1u)) >> 16;
}
__device__ __forceinline__ uint pack2(float lo, float hi) {
    return bf16_rne(lo) | (bf16_rne(hi) << 16);
}
__device__ __forceinline__ float bf_lo(uint u) { return __uint_as_float(u << 16); }
__device__ __forceinline__ float bf_hi(uint u) { return __uint_as_float(u & 0xffff0000u); }
__device__ __forceinline__ float bf_us(ushort u) { return __uint_as_float(((uint)u) << 16); }

// pack two floats -> f16x2 (RNE)
__device__ __forceinline__ uint ph2(float lo, float hi) {
    __fp16 l = (__fp16)lo, h = (__fp16)hi;
    return (uint)__builtin_bit_cast(ushort, l) | ((uint)__builtin_bit_cast(ushort, h) << 16);
}

#if defined(__has_builtin) && __has_builtin(__builtin_amdgcn_fdot2)
__device__ __forceinline__ float fdot2f(uint u, half2v w, float c) {
    return __builtin_amdgcn_fdot2(__builtin_bit_cast(half2v, u), w, c, false);
}
#else
__device__ __forceinline__ float fdot2f(uint u, half2v w, float c) {
    half2v a = __builtin_bit_cast(half2v, u);
    return c + (float)a.x * (float)w.x + (float)a.y * (float)w.y;
}
#endif

// ---------------- x -> bf16 pack ----------------
__global__ __launch_bounds__(256) void pack_x_kernel(
    const float* __restrict__ x, ushort* __restrict__ xb)
{
    int i = blockIdx.x * 256 + threadIdx.x;     // over N*D/4
    if (i >= N_NODES * D / 4) return;
    float4 f = ((const float4*)x)[i];
    ((uint2*)xb)[i] = make_uint2(pack2(f.x, f.y), pack2(f.z, f.w));
}

// ---- A1: per-block coarse histogram (LDS), write count matrix ----
// r12: int4-vectorized dst loads (one int4 per thread; A_EPB=1024 = 256*4).
__global__ __launch_bounds__(256) void countA_kernel(
    const int* __restrict__ dst, int* __restrict__ cntM)
{
    __shared__ int h[CB];
    const int t = threadIdx.x;
    for (int i = t; i < CB; i += 256) h[i] = 0;
    __syncthreads();
    const int q0 = blockIdx.x * (A_EPB / 4);
    const int q = q0 + t;
    if (q < N_EDGES / 4) {
        int4 dd = ((const int4*)dst)[q];
        atomicAdd(&h[dd.x >> BSH], 1);
        atomicAdd(&h[dd.y >> BSH], 1);
        atomicAdd(&h[dd.z >> BSH], 1);
        atomicAdd(&h[dd.w >> BSH], 1);
    }
    __syncthreads();
    for (int i = t; i < CB; i += 256) cntM[blockIdx.x * CB + i] = h[i];
}

// ---- S1: per-bucket exclusive scan over blocks (A_NB <= 2048) ----
// 1024 threads, 2 elements per thread (pair-local reconstruction).
__global__ __launch_bounds__(1024) void scanS1_kernel(
    const int* __restrict__ cntM, int* __restrict__ exclM, int* __restrict__ btot)
{
    __shared__ int s[1024];
    const int t = threadIdx.x;
    const int b = blockIdx.x;
    const int r0 = 2 * t, r1 = 2 * t + 1;
    int v0 = (r0 < A_NB) ? cntM[r0 * CB + b] : 0;
    int v1 = (r1 < A_NB) ? cntM[r1 * CB + b] : 0;
    s[t] = v0 + v1;
    __syncthreads();
    for (int off = 1; off < 1024; off <<= 1) {
        int u = (t >= off) ? s[t - off] : 0;
        __syncthreads();
        s[t] += u;
        __syncthreads();
    }
    int base0 = s[t] - v0 - v1;                 // exclusive prefix before pair
    if (r0 < A_NB) exclM[r0 * CB + b] = base0;
    if (r1 < A_NB) exclM[r1 * CB + b] = base0 + v0;
    if (t == 1023) btot[b] = s[1023];
}

// ---- S2: exclusive scan of bucket totals -> bucket bases ----
__global__ __launch_bounds__(1024) void scanS2_kernel(
    const int* __restrict__ btot, int* __restrict__ bbase, int* __restrict__ row_ptr)
{
    __shared__ int s[1024];
    const int t = threadIdx.x;
    int v = (t < CB) ? btot[t] : 0;
    s[t] = v;
    __syncthreads();
    for (int off = 1; off < 1024; off <<= 1) {
        int u = (t >= off) ? s[t - off] : 0;
        __syncthreads();
        s[t] += u;
        __syncthreads();
    }
    if (t < CB) bbase[t] = s[t] - v;
    if (t == 0) row_ptr[N_NODES] = N_EDGES;
}

// ---- A3: coarse scatter (zero global atomics), SoA 20B/edge ----
// ea_tmp: f16x8 edge attrs (16B); sd_tmp: src (bits 0..19) | dst&511 (bits 20..28)
__global__ __launch_bounds__(256) void scatterA_kernel(
    const int*   __restrict__ src,
    const int*   __restrict__ dst,
    const float* __restrict__ edge_attr,
    const int*   __restrict__ exclM,
    const int*   __restrict__ bbase,
    uint4*       __restrict__ ea_tmp,
    uint*        __restrict__ sd_tmp)
{
    __shared__ int cur[CB];
    const int t = threadIdx.x;
    for (int i = t; i < CB; i += 256)
        cur[i] = bbase[i] + exclM[blockIdx.x * CB + i];
    __syncthreads();
    const int e0 = blockIdx.x * A_EPB;
    const float4* ea4 = (const float4*)edge_attr;
    for (int j = 0; j < A_EPB; j += 256) {
        int e = e0 + j + t;
        if (e >= N_EDGES) continue;
        int dn = dst[e];
        int pos = atomicAdd(&cur[dn >> BSH], 1);
        float4 a = ea4[(long)e * 2];
        float4 c = ea4[(long)e * 2 + 1];
        ea_tmp[pos] = make_uint4(ph2(a.x, a.y), ph2(a.z, a.w),
                                 ph2(c.x, c.y), ph2(c.z, c.w));
        sd_tmp[pos] = (uint)src[e] | ((uint)(dn & (BKN - 1)) << 20);
    }
}

// ---- B: per-bucket fine scatter -> SoA {ea16, srcf} + exact row_ptr ----
// FB_SPLIT sub-blocks per bucket, split by node-ownership.
__global__ __launch_bounds__(512) void fineB_kernel(
    const uint4* __restrict__ ea_tmp,
    const uint*  __restrict__ sd_tmp,
    const int*   __restrict__ bbase,
    int*         __restrict__ row_ptr,
    uint4*       __restrict__ ea16,
    int*         __restrict__ srcf)
{
    __shared__ int h[BKN];
    __shared__ int ex[BKN];
    const int t = threadIdx.x;
    const int b = blockIdx.x / FB_SPLIT;          // bucket
    const int s = blockIdx.x % FB_SPLIT;          // owned half: nl>>8 == s
    const int e0 = bbase[b];
    const int e1 = (b == CB - 1) ? N_EDGES : bbase[b + 1];

    h[t] = 0;
    __syncthreads();
    for (int r = e0 + t; r < e1; r += 512)
        atomicAdd(&h[sd_tmp[r] >> 20], 1);
    __syncthreads();
    ex[t] = h[t];
    __syncthreads();
    for (int off = 1; off < BKN; off <<= 1) {
        int u = (t >= off) ? ex[t - off] : 0;
        __syncthreads();
        ex[t] += u;
        __syncthreads();
    }
    {
        int excl = ex[t] - h[t];
        int n = b * BKN + t;
        if (s == 0 && n < N_NODES) row_ptr[n] = e0 + excl;
        h[t] = e0 + excl;
    }
    __syncthreads();
    for (int r = e0 + t; r < e1; r += 512) {
        uint sd = sd_tmp[r];
        int nl = (int)(sd >> 20);
        if ((nl >> 8) == s) {                     // owned node -> place it
            uint4 ea = ea_tmp[r];
            int pos = atomicAdd(&h[nl], 1);
            ea16[pos] = ea;
            srcf[pos] = (int)(sd & 0xFFFFFu);
        }
    }
}

// ---------------- fused GINE layer (r9-measured config, 66.5us) ----------------
// Half-wave (32 lanes) per node. Per-edge record data broadcast to the
// half-wave by SAME-ADDRESS vector loads: zero DS ops in the inner loop.
// 4-edge chunks + masked tail; plain loads (nt-loads hurt: +10MB FETCH).
// r12: last layer writes f32 only (dead bf16 store skipped).
__global__ __launch_bounds__(256) void gine_fused4_kernel(
    const ushort* __restrict__ xb_in, ushort* __restrict__ xb_out,
    float* __restrict__ f32_out, const int* __restrict__ row_ptr,
    const uint4* __restrict__ ea16, const int* __restrict__ srcf,
    const float* __restrict__ W, const float* __restrict__ b,
    const float* __restrict__ We, const float* __restrict__ be)
{
    __shared__ float W_s[D * D];
    const int t = threadIdx.x;
    for (int i = t; i < D * D; i += 256) W_s[i] = W[i];

    const int n = blockIdx.x * 8 + (t >> 5);
    const int d = t & 31;

    half2v wep[4];
#pragma unroll
    for (int k = 0; k < 4; ++k) {
        wep[k].x = (__fp16)We[(2 * k) * D + d];
        wep[k].y = (__fp16)We[(2 * k + 1) * D + d];
    }
    const float bed = be[d];
    const float bd  = b[d];
    __syncthreads();
    if (n >= N_NODES) return;

    const int row = row_ptr[n], rend = row_ptr[n + 1];
    float selfx = bf_us(xb_in[n * D + d]);

    float acc = 0.0f;
    int pos = row;
    // main loop: full chunks of 4 edges, no masking
    for (; pos + 4 <= rend; pos += 4) {
        uint4 ev[4];
        int sj[4];
#pragma unroll
        for (int j = 0; j < 4; ++j) {
            ev[j] = ea16[pos + j];     // 16B, half-wave-uniform addr -> broadcast
            sj[j] = srcf[pos + j];     // 4B, half-wave-uniform addr -> broadcast
        }
        float xv[4];
#pragma unroll
        for (int j = 0; j < 4; ++j)
            xv[j] = bf_us(xb_in[sj[j] * D + d]);
#pragma unroll
        for (int j = 0; j < 4; ++j) {
            float e = fdot2f(ev[j].w, wep[3],
                      fdot2f(ev[j].z, wep[2],
                      fdot2f(ev[j].y, wep[1],
                      fdot2f(ev[j].x, wep[0], bed))));
            acc += fmaxf(xv[j] + e, 0.0f);
        }
    }
    // tail chunk (1..3 edges), masked
    if (pos < rend) {
        const int rem = rend - pos;
        uint4 ev[4];
        int sj[4];
#pragma unroll
        for (int j = 0; j < 4; ++j) {
            int idx = pos + ((j < rem) ? j : 0);   // clamp: always in-bounds
            ev[j] = ea16[idx];
            sj[j] = srcf[idx];
        }
        float xv[4];
#pragma unroll
        for (int j = 0; j < 4; ++j)
            xv[j] = bf_us(xb_in[sj[j] * D + d]);
#pragma unroll
        for (int j = 0; j < 4; ++j) {
            float e = fdot2f(ev[j].w, wep[3],
                      fdot2f(ev[j].z, wep[2],
                      fdot2f(ev[j].y, wep[1],
                      fdot2f(ev[j].x, wep[0], bed))));
            float msg = fmaxf(xv[j] + e, 0.0f);
            acc += (j < rem) ? msg : 0.0f;
        }
    }

    float h = selfx + acc;
    float o = bd;
#pragma unroll
    for (int k = 0; k < D; ++k)
        o += __shfl(h, k, 32) * W_s[k * D + d];
    o = o > 0.0f ? o : NEG_SLOPE * o;
    if (f32_out) f32_out[n * D + d] = o;
    else         xb_out[n * D + d] = (ushort)bf16_rne(o);
}

// =================== mid-tier (CSR build + bf16 layer) ===================
__global__ __launch_bounds__(256) void hist_kernel(
    const int* __restrict__ dst, int* __restrict__ deg)
{
    int i = blockIdx.x * 256 + threadIdx.x;
    if (i >= N_EDGES / 4) return;
    int4 dd = ((const int4*)dst)[i];
    atomicAdd(&deg[dd.x], 1);
    atomicAdd(&deg[dd.y], 1);
    atomicAdd(&deg[dd.z], 1);
    atomicAdd(&deg[dd.w], 1);
}

__global__ __launch_bounds__(1024) void scan_phase1(
    const int* __restrict__ deg, int* __restrict__ bsums)
{
    __shared__ int s[1024];
    int t = threadIdx.x;
    int i = blockIdx.x * 1024 + t;
    s[t] = (i < N_NODES) ? deg[i] : 0;
    __syncthreads();
    for (int off = 512; off > 0; off >>= 1) {
        if (t < off) s[t] += s[t + off];
        __syncthreads();
    }
    if (t == 0) bsums[blockIdx.x] = s[0];
}

__global__ __launch_bounds__(128) void scan_phase2(int* __restrict__ bsums)
{
    __shared__ int s[128];
    int t = threadIdx.x;
    int v = (t < NBLK) ? bsums[t] : 0;
    s[t] = v;
    __syncthreads();
    for (int off = 1; off < 128; off <<= 1) {
        int u = (t >= off) ? s[t - off] : 0;
        __syncthreads();
        s[t] += u;
        __syncthreads();
    }
    if (t < NBLK) bsums[t] = s[t] - v;
}

__global__ __launch_bounds__(1024) void scan_phase3(
    const int* __restrict__ deg, const int* __restrict__ bsums,
    int* __restrict__ row_ptr, int* __restrict__ offs)
{
    __shared__ int s[1024];
    int t = threadIdx.x;
    int i = blockIdx.x * 1024 + t;
    int v = (i < N_NODES) ? deg[i] : 0;
    s[t] = v;
    __syncthreads();
    for (int off = 1; off < 1024; off <<= 1) {
        int u = (t >= off) ? s[t - off] : 0;
        __syncthreads();
        s[t] += u;
        __syncthreads();
    }
    int excl = bsums[blockIdx.x] + s[t] - v;
    if (i < N_NODES) { row_ptr[i] = excl; offs[i] = excl; }
    else if (i == N_NODES) row_ptr[i] = excl;
}

__global__ __launch_bounds__(256) void scatter_rec_kernel(
    const int* __restrict__ src, const int* __restrict__ dst,
    const float* __restrict__ edge_attr, int* __restrict__ offs,
    uint* __restrict__ rec)
{
    int e = blockIdx.x * 256 + threadIdx.x;
    if (e >= N_EDGES) return;
    int pos = atomicAdd(&offs[dst[e]], 1);
    const float4* ea4 = (const float4*)edge_attr;
    float4 a = ea4[(long)e * 2];
    float4 c = ea4[(long)e * 2 + 1];
    uint* r = rec + (long)pos * 8;
    *(uint4*)r = make_uint4((uint)src[e], pack2(a.x, a.y), pack2(a.z, a.w), pack2(c.x, c.y));
    r[4] = pack2(c.z, c.w);
}

__global__ __launch_bounds__(256) void gine_fused2_kernel(
    const ushort* __restrict__ xb_in, ushort* __restrict__ xb_out,
    float* __restrict__ f32_out, const int* __restrict__ row_ptr,
    const uint* __restrict__ rec,
    const float* __restrict__ W, const float* __restrict__ b,
    const float* __restrict__ We, const float* __restrict__ be)
{
    __shared__ float W_s[D * D];
    __shared__ float We_s[ED * D];
    __shared__ float b_s[D];
    __shared__ float be_s[D];
    const int t = threadIdx.x;
    for (int i = t; i < D * D; i += 256) W_s[i] = W[i];
    if (t < ED * D) We_s[t] = We[t];
    if (t < D) { b_s[t] = b[t]; be_s[t] = be[t]; }
    __syncthreads();
    const int n = blockIdx.x * 8 + (t >> 5);
    const int d = t & 31;
    if (n >= N_NODES) return;
    float wer[ED];
#pragma unroll
    for (int k = 0; k < ED; ++k) wer[k] = We_s[k * D + d];
    const float bed = be_s[d];
    const int row = row_ptr[n], rend = row_ptr[n + 1];
    float selfx = bf_us(xb_in[n * D + d]);
    float acc = 0.0f;
    for (int pos = row; pos < rend; pos += 8) {
        const int rem = rend - pos;
        const uint2* rp = (const uint2*)(rec + (long)pos * 8);
        uint2 v = rp[d];
        int srcs[8];
#pragma unroll
        for (int j = 0; j < 8; ++j) srcs[j] = __shfl((int)v.x, 4 * j, 32);
        const int s0 = srcs[0];
        float xv[8];
#pragma unroll
        for (int j = 0; j < 8; ++j) {
            int sj = (j < rem) ? srcs[j] : s0;
            xv[j] = bf_us(xb_in[sj * D + d]);
        }
#pragma unroll
        for (int j = 0; j < 8; ++j) {
            uint u01 = (uint)__shfl((int)v.y, 4 * j, 32);
            uint u23 = (uint)__shfl((int)v.x, 4 * j + 1, 32);
            uint u45 = (uint)__shfl((int)v.y, 4 * j + 1, 32);
            uint u67 = (uint)__shfl((int)v.x, 4 * j + 2, 32);
            float e = bed;
            e += bf_lo(u01) * wer[0]; e += bf_hi(u01) * wer[1];
            e += bf_lo(u23) * wer[2]; e += bf_hi(u23) * wer[3];
            e += bf_lo(u45) * wer[4]; e += bf_hi(u45) * wer[5];
            e += bf_lo(u67) * wer[6]; e += bf_hi(u67) * wer[7];
            float msg = fmaxf(xv[j] + e, 0.0f);
            acc += (j < rem) ? msg : 0.0f;
        }
    }
    float h = selfx + acc;
    float o = b_s[d];
#pragma unroll
    for (int k = 0; k < D; ++k)
        o += __shfl(h, k, 32) * W_s[k * D + d];
    o = o > 0.0f ? o : NEG_SLOPE * o;
    xb_out[n * D + d] = (ushort)bf16_rne(o);
    if (f32_out) f32_out[n * D + d] = o;
}

// =================== round-1 fallback ===================
__global__ __launch_bounds__(256) void gine_edge_kernel(
    const float* __restrict__ x, const float* __restrict__ edge_attr,
    const float* __restrict__ We, const float* __restrict__ be,
    const int* __restrict__ src, const int* __restrict__ dst,
    float* __restrict__ agg)
{
    __shared__ float We_s[ED * D];
    __shared__ float be_s[D];
    int t = threadIdx.x;
    if (t < ED * D) We_s[t] = We[t];
    if (t < D) be_s[t] = be[t];
    __syncthreads();
    long gtid = (long)blockIdx.x * blockDim.x + t;
    int e = (int)(gtid >> 5), d = (int)(gtid & 31);
    if (e >= N_EDGES) return;
    int s = src[e], dn = dst[e];
    float acc = be_s[d];
#pragma unroll
    for (int k = 0; k < ED; ++k)
        acc += edge_attr[(long)e * ED + k] * We_s[k * D + d];
    float m = fmaxf(x[(long)s * D + d] + acc, 0.0f);
    atomicAdd(&agg[(long)dn * D + d], m);
}

__global__ __launch_bounds__(256) void gine_node_kernel(
    float* __restrict__ x, const float* __restrict__ agg,
    const float* __restrict__ W, const float* __restrict__ b)
{
    __shared__ float W_s[D * D];
    __shared__ float b_s[D];
    int t = threadIdx.x;
    for (int i = t; i < D * D; i += 256) W_s[i] = W[i];
    if (t < D) b_s[t] = b[t];
    __syncthreads();
    long gtid = (long)blockIdx.x * blockDim.x + t;
    int n = (int)(gtid >> 5), d = (int)(gtid & 31);
    if (n >= N_NODES) return;
    float h = x[(long)n * D + d] + agg[(long)n * D + d];
    float acc = b_s[d];
#pragma unroll
    for (int k = 0; k < D; ++k)
        acc += __shfl(h, k, D) * W_s[k * D + d];
    x[(long)n * D + d] = acc > 0.0f ? acc : NEG_SLOPE * acc;
}

// =================== launch ===================
extern "C" void kernel_launch(void* const* d_in, const int* in_sizes, int n_in,
                              void* d_out, int out_size, void* d_ws, size_t ws_size,
                              hipStream_t stream) {
    const float* x_in      = (const float*)d_in[0];
    const float* edge_attr = (const float*)d_in[1];
    const float* W         = (const float*)d_in[2];
    const float* b         = (const float*)d_in[3];
    const float* We        = (const float*)d_in[4];
    const float* be        = (const float*)d_in[5];
    const int*   ei        = (const int*)d_in[6];
    const int* src = ei;
    const int* dst = ei + N_EDGES;

    const size_t xbytes  = (size_t)N_NODES * D * sizeof(float);
    const size_t xbbytes = (size_t)N_NODES * D * sizeof(ushort);  // 6.4 MB

    auto align = [](size_t v) { return (v + 255) & ~(size_t)255; };
    size_t off_xba  = 0;
    size_t off_rp   = align(off_xba + xbbytes);                    // row_ptr N+1
    size_t off_cnt  = align(off_rp + (N_NODES + 1) * sizeof(int)); // cntM / deg
    size_t off_excl = align(off_cnt + (size_t)A_NB * CB * sizeof(int));  // exclM / offs
    size_t off_bt   = align(off_excl + (size_t)A_NB * CB * sizeof(int)); // btot / bsums
    size_t off_bb   = align(off_bt + CB * sizeof(int));            // bbase
    size_t off_ea   = align(off_bb + CB * sizeof(int));            // ea16 (E+8)*16B
    size_t off_src  = align(off_ea + ((size_t)N_EDGES + 8) * 16);  // srcf (E+8)*4B
    size_t off_eat  = align(off_src + ((size_t)N_EDGES + 8) * 4);  // ea_tmp E*16B / xbB
    size_t off_sdt  = align(off_eat + ((size_t)N_EDGES + 8) * 16); // sd_tmp E*4B
    size_t need_big = off_sdt + ((size_t)N_EDGES + 8) * 4 + 256;
    // mid tier: rec (E*32B) at off_ea, xbB after
    size_t off_mrec = off_ea;
    size_t off_mxbb = align(off_mrec + ((size_t)N_EDGES + 8) * 32);
    size_t need_mid = off_mxbb + xbbytes + 256;

    char* ws = (char*)d_ws;
    ushort* xbA    = (ushort*)(ws + off_xba);
    int*   row_ptr = (int*)   (ws + off_rp);
    int*   cntM    = (int*)   (ws + off_cnt);
    int*   exclM   = (int*)   (ws + off_excl);
    int*   btot    = (int*)   (ws + off_bt);
    int*   bbase   = (int*)   (ws + off_bb);
    uint4* ea16    = (uint4*) (ws + off_ea);
    int*   srcf    = (int*)   (ws + off_src);
    uint4* ea_tmp  = (uint4*) (ws + off_eat);
    uint*  sd_tmp  = (uint*)  (ws + off_sdt);
    ushort* xbB    = (ushort*)(ws + off_eat);   // aliases ea_tmp (dead after fineB)
    float* xout    = (float*)d_out;

    if (ws_size >= need_big) {
        pack_x_kernel<<<(N_NODES * D / 4 + 255) / 256, 256, 0, stream>>>(x_in, xbA);
        countA_kernel<<<A_NB, 256, 0, stream>>>(dst, cntM);
        scanS1_kernel<<<CB, 1024, 0, stream>>>(cntM, exclM, btot);
        scanS2_kernel<<<1, 1024, 0, stream>>>(btot, bbase, row_ptr);
        scatterA_kernel<<<A_NB, 256, 0, stream>>>(src, dst, edge_attr, exclM, bbase,
                                                  ea_tmp, sd_tmp);
        fineB_kernel<<<CB * FB_SPLIT, 512, 0, stream>>>(ea_tmp, sd_tmp, bbase, row_ptr,
                                                        ea16, srcf);

        dim3 blk(256), grid((N_NODES + 7) / 8);
        gine_fused4_kernel<<<grid, blk, 0, stream>>>(xbA, xbB, nullptr, row_ptr, ea16, srcf,
            W, b, We, be);
        gine_fused4_kernel<<<grid, blk, 0, stream>>>(xbB, xbA, nullptr, row_ptr, ea16, srcf,
            W + D * D, b + D, We + ED * D, be + D);
        gine_fused4_kernel<<<grid, blk, 0, stream>>>(xbA, xbB, xout, row_ptr, ea16, srcf,
            W + 2 * D * D, b + 2 * D, We + 2 * ED * D, be + 2 * D);
    } else if (ws_size >= need_mid) {
        int* deg  = cntM;
        int* offs = exclM;
        int* bsums = btot;
        uint* rec = (uint*)(ws + off_mrec);
        ushort* xbBm = (ushort*)(ws + off_mxbb);
        pack_x_kernel<<<(N_NODES * D / 4 + 255) / 256, 256, 0, stream>>>(x_in, xbA);
        hipMemsetAsync(deg, 0, N_NODES * sizeof(int), stream);
        hist_kernel<<<(N_EDGES / 4 + 255) / 256, 256, 0, stream>>>(dst, deg);
        scan_phase1<<<NBLK, 1024, 0, stream>>>(deg, bsums);
        scan_phase2<<<1, 128, 0, stream>>>(bsums);
        scan_phase3<<<NBLK, 1024, 0, stream>>>(deg, bsums, row_ptr, offs);
        scatter_rec_kernel<<<(N_EDGES + 255) / 256, 256, 0, stream>>>(
            src, dst, edge_attr, offs, rec);
        dim3 blk(256), grid((N_NODES + 7) / 8);
        gine_fused2_kernel<<<grid, blk, 0, stream>>>(xbA, xbBm, nullptr, row_ptr, rec,
            W, b, We, be);
        gine_fused2_kernel<<<grid, blk, 0, stream>>>(xbBm, xbA, nullptr, row_ptr, rec,
            W + D * D, b + D, We + ED * D, be + D);
        gine_fused2_kernel<<<grid, blk, 0, stream>>>(xbA, xbBm, xout, row_ptr, rec,
            W + 2 * D * D, b + 2 * D, We + 2 * ED * D, be + 2 * D);
    } else {
        float* x = (float*)d_out;
        float* agg = (float*)d_ws;
        hipMemcpyAsync(x, x_in, xbytes, hipMemcpyDeviceToDevice, stream);
        dim3 eblk(256), egrid(((long)N_EDGES * D + 255) / 256);
        dim3 nblk(256), ngrid(((long)N_NODES * D + 255) / 256);
        for (int l = 0; l < 3; ++l) {
            hipMemsetAsync(agg, 0, xbytes, stream);
            gine_edge_kernel<<<egrid, eblk, 0, stream>>>(
                x, edge_attr, We + (size_t)l * ED * D, be + (size_t)l * D, src, dst, agg);
            gine_node_kernel<<<ngrid, nblk, 0, stream>>>(
                x, agg, W + (size_t)l * D * D, b + (size_t)l * D);
        }
    }
}